// Round 1
// 1321.485 us; speedup vs baseline: 1.0595x; 1.0595x over previous
//
#include <hip/hip_runtime.h>
#include <cstdint>

#define D_  2048
#define H_  16
#define HD_ 128
#define FF_ 8192
#define T_  2048
#define B_  2
#define BT_ (B_*T_)
#define NP_ (B_*H_)        // 32 (b,h) pairs
#define CH_ 8              // pairs per attention chunk
#define NCH_ (NP_/CH_)     // 4 chunks
#define QKVLD_ (3*D_)      // fused qkv row stride (6144)

typedef __attribute__((ext_vector_type(8))) _Float16 half8;
typedef __attribute__((ext_vector_type(4))) float   floatx4;

// async global->LDS, 16B per lane; LDS dest = wave-uniform base + lane*16
__device__ __forceinline__ void gl_lds16(const void* g, void* l) {
  __builtin_amdgcn_global_load_lds(
      (const __attribute__((address_space(1))) void*)(uintptr_t)g,
      (__attribute__((address_space(3))) void*)(uintptr_t)l,
      16, 0, 0);
}

// ---------------- weight convert + transpose: W[K][N] f32 -> Wt[N][K] f16 ----
__global__ void wconv_kernel(const float* __restrict__ W, _Float16* __restrict__ Wt,
                             int K, int N) {
  __shared__ float tile[32][33];
  int n0 = blockIdx.x * 32, k0 = blockIdx.y * 32;
  int tx = threadIdx.x, ty = threadIdx.y;   // 32 x 8
#pragma unroll
  for (int r = 0; r < 32; r += 8)
    tile[ty + r][tx] = W[(size_t)(k0 + ty + r) * N + n0 + tx];
  __syncthreads();
#pragma unroll
  for (int r = 0; r < 32; r += 8)
    Wt[(size_t)(n0 + ty + r) * K + k0 + tx] = (_Float16)tile[tx][ty + r];
}

// ---------------- rmsnorm: fp32 row -> fp16 row --------------------------------
__global__ void rmsnorm_kernel(const float* __restrict__ x, const float* __restrict__ g,
                               _Float16* __restrict__ out) {
  int row = blockIdx.x, tid = threadIdx.x;
  const float4* xr = (const float4*)(x + (size_t)row * D_);
  float4 v1 = xr[tid], v2 = xr[tid + 256];
  float ss = v1.x*v1.x + v1.y*v1.y + v1.z*v1.z + v1.w*v1.w
           + v2.x*v2.x + v2.y*v2.y + v2.z*v2.z + v2.w*v2.w;
  __shared__ float red[256];
  red[tid] = ss; __syncthreads();
  for (int s = 128; s > 0; s >>= 1) { if (tid < s) red[tid] += red[tid + s]; __syncthreads(); }
  float rs = rsqrtf(red[0] * (1.0f / D_) + 1e-6f);
  float4 ga = ((const float4*)g)[tid], gb = ((const float4*)g)[tid + 256];
  _Float16* orow = out + (size_t)row * D_;
  _Float16 t[4] __attribute__((aligned(8)));
  t[0] = (_Float16)(v1.x * rs * ga.x);
  t[1] = (_Float16)(v1.y * rs * ga.y);
  t[2] = (_Float16)(v1.z * rs * ga.z);
  t[3] = (_Float16)(v1.w * rs * ga.w);
  *(uint2*)(orow + tid * 4) = *(const uint2*)t;
  t[0] = (_Float16)(v2.x * rs * gb.x);
  t[1] = (_Float16)(v2.y * rs * gb.y);
  t[2] = (_Float16)(v2.z * rs * gb.z);
  t[3] = (_Float16)(v2.w * rs * gb.w);
  *(uint2*)(orow + (tid + 256) * 4) = *(const uint2*)t;
}

// ================================================================================
// Deep-pipelined dense GEMM: C = A @ Bt^T.
// A: M x K f16 (lda), Bt: N x K f16 (ldb), C: M x N (ldc).
// BM=256, BN=64*NJ (NJ=4 -> 256, NJ=2 -> 128), BK=32.
// 512 threads = 8 waves (2M x 4N); per-wave output 128 x (16*NJ).
// LDS: 4-slot ring (A: 4x16KB, B: 4x(BN*64)B) -> 128 KiB (NJ4) / 96 KiB (NJ2),
// staged 3 K-tiles ahead with global_load_lds + counted vmcnt (never 0 in
// steady state). Column swizzle (involution c ^= (row>>1)&3 on 16B chunks)
// applied on the *global source* at stage time and on the ds_read address,
// so LDS dest stays linear (global_load_lds requirement) and ds_read_b128 is
// bank-conflict-free. Requires M%256==0, N%BN==0, K%32==0, K>=128.
template<int NJ, int ADDRES>
__global__ __launch_bounds__(512, 2) void gemm256(
    const _Float16* __restrict__ A, const _Float16* __restrict__ Bt,
    void* __restrict__ Cv, const float* __restrict__ Res,
    int M, int N, int K, int lda, int ldb, int ldc)
{
  constexpr int BN    = 64 * NJ;
  constexpr int RPT   = 2 + NJ / 2;   // stage rounds per K-tile (A:2, B:NJ/2)
  constexpr int ASLOT = 256 * 32;     // f16 elems per A ring slot
  constexpr int BSLOT = BN * 32;
  extern __shared__ _Float16 smem[];
  _Float16* As = smem;                // [4][ASLOT]
  _Float16* Bs = smem + 4 * ASLOT;    // [4][BSLOT]

  const int tid  = threadIdx.x;
  const int lane = tid & 63;
  const int w    = tid >> 6;          // 0..7
  const int wm   = w >> 2;            // 0..1  (M wave row)
  const int wn   = w & 3;             // 0..3  (N wave col)
  const int l15  = lane & 15, q4 = lane >> 4;
  const int m0   = blockIdx.y * 256;
  const int n0   = blockIdx.x * BN;
  const int NT   = K >> 5;

  // staging: wave w covers rows [r*128 + w*16, +16), 4 x 16B chunks per row.
  const int srow = w * 16 + (lane >> 2);
  const int scol = (((lane & 3) ^ ((lane >> 3) & 3)) << 3);  // pre-swizzled col
  const _Float16* Ag = A  + (size_t)(m0 + srow) * lda + scol;
  const _Float16* Bg = Bt + (size_t)(n0 + srow) * ldb + scol;
  const int ldsW = w * 512;           // elems: wave base within a round

  // ds_read: logical chunk q4 lives at physical chunk q4 ^ ((row>>1)&3)
  const int chunk = ((q4 ^ ((l15 >> 1) & 3)) << 3);
  const int arow  = wm * 128 + l15;
  const int brow  = wn * 16 * NJ + l15;

  floatx4 acc[8][NJ];
#pragma unroll
  for (int i = 0; i < 8; ++i)
#pragma unroll
    for (int j = 0; j < NJ; ++j)
#pragma unroll
      for (int r = 0; r < 4; ++r) acc[i][j][r] = 0.0f;

  auto stage = [&](int t, int r) {
    const int slot = t & 3;
    if (r < 2) {
      gl_lds16(Ag + (size_t)(r * 128) * lda + t * 32,
               As + slot * ASLOT + r * 4096 + ldsW);
    } else {
      if constexpr (NJ == 4) {
        const int rb = r - 2;
        gl_lds16(Bg + (size_t)(rb * 128) * ldb + t * 32,
                 Bs + slot * BSLOT + rb * 4096 + ldsW);
      } else {
        gl_lds16(Bg + t * 32, Bs + slot * BSLOT + ldsW);
      }
    }
  };

  // prologue: stage tiles 0..2 into slots 0..2; ensure tile 0 landed
  // (leave tiles 1,2 = 2*RPT instructions in flight).
  for (int t = 0; t < 3; ++t)
    for (int r = 0; r < RPT; ++r) stage(t, r);
  if constexpr (NJ == 4) asm volatile("s_waitcnt vmcnt(8)" ::: "memory");
  else                   asm volatile("s_waitcnt vmcnt(6)" ::: "memory");
  __builtin_amdgcn_s_barrier();

  half8 bf[NJ];
  for (int t = 0; t < NT; ++t) {
    const int slot = t & 3;
    const _Float16* aS = As + slot * ASLOT + arow * 32 + chunk;
    const _Float16* bS = Bs + slot * BSLOT + brow * 32 + chunk;
    const bool pf = (t + 3 < NT);

    // ---- phase 0: this wave's A rows 0..63, all B frags ----
    half8 af[4];
#pragma unroll
    for (int i = 0; i < 4; ++i) af[i] = *(const half8*)(aS + i * 16 * 32);
#pragma unroll
    for (int j = 0; j < NJ; ++j) bf[j] = *(const half8*)(bS + j * 16 * 32);
    if (pf) { stage(t + 3, 0); stage(t + 3, 1); }   // into slot (t-1)&3: safe
    __builtin_amdgcn_s_barrier();
    __builtin_amdgcn_s_setprio(1);
#pragma unroll
    for (int i = 0; i < 4; ++i)
#pragma unroll
      for (int j = 0; j < NJ; ++j)
        acc[i][j] = __builtin_amdgcn_mfma_f32_16x16x32_f16(af[i], bf[j], acc[i][j], 0, 0, 0);
    __builtin_amdgcn_s_setprio(0);
    __builtin_amdgcn_s_barrier();

    // ---- phase 1: A rows 64..127 ----
#pragma unroll
    for (int i = 0; i < 4; ++i) af[i] = *(const half8*)(aS + (64 + i * 16) * 32);
    if (pf) {
#pragma unroll
      for (int r = 2; r < RPT; ++r) stage(t + 3, r);
    }
    __builtin_amdgcn_s_barrier();
    __builtin_amdgcn_s_setprio(1);
#pragma unroll
    for (int i = 0; i < 4; ++i)
#pragma unroll
      for (int j = 0; j < NJ; ++j)
        acc[4 + i][j] = __builtin_amdgcn_mfma_f32_16x16x32_f16(af[i], bf[j], acc[4 + i][j], 0, 0, 0);
    __builtin_amdgcn_s_setprio(0);

    // end-of-tile: tile t+1 must be fully landed before next iteration's reads.
    // newer-than-tile-(t+1) instructions = RPT*[(t+2<NT)] + RPT*[(t+3<NT)].
    if (pf) {
      if constexpr (NJ == 4) asm volatile("s_waitcnt vmcnt(8)" ::: "memory");
      else                   asm volatile("s_waitcnt vmcnt(6)" ::: "memory");
    } else if (t + 2 < NT) {
      if constexpr (NJ == 4) asm volatile("s_waitcnt vmcnt(4)" ::: "memory");
      else                   asm volatile("s_waitcnt vmcnt(3)" ::: "memory");
    } else {
      asm volatile("s_waitcnt vmcnt(0)" ::: "memory");
    }
    __builtin_amdgcn_s_barrier();
  }

  // epilogue: C/D layout col=lane&15, row=(lane>>4)*4+r
  const int crow = m0 + wm * 128 + q4 * 4;
  const int ccol = n0 + wn * 16 * NJ + l15;
#pragma unroll
  for (int i = 0; i < 8; ++i)
#pragma unroll
    for (int j = 0; j < NJ; ++j)
#pragma unroll
      for (int r = 0; r < 4; ++r) {
        size_t o = (size_t)(crow + i * 16 + r) * ldc + (ccol + j * 16);
        if (ADDRES) ((float*)Cv)[o] = acc[i][j][r] + Res[o];
        else        ((_Float16*)Cv)[o] = (_Float16)acc[i][j][r];
      }
}

// ---------------- old 128x128 MFMA GEMM (attention scores / PV only) ------------
template<int CMODE, int ADDRES, int LOCALS>
__global__ __launch_bounds__(256, 3) void gemm_bt(
    const _Float16* __restrict__ A, const _Float16* __restrict__ Bt,
    void* __restrict__ Cv, const float* __restrict__ Res,
    int M, int N, int K, int lda, int ldb, int ldc, int pair0,
    long long sAd, long long sAm, long long sBd, long long sBm,
    long long sCd, long long sCm)
{
  int zl = blockIdx.z;
  int p = pair0 + zl;
  long long aoff = (LOCALS & 1) ? (long long)zl * sAd
                                : (long long)(p >> 4) * sAd + (long long)(p & 15) * sAm;
  long long boff = (long long)(p >> 4) * sBd + (long long)(p & 15) * sBm;
  long long coff = (LOCALS & 2) ? (long long)zl * sCd
                                : (long long)(p >> 4) * sCd + (long long)(p & 15) * sCm;
  const _Float16* Ab = A + (size_t)aoff;
  const _Float16* Bb = Bt + (size_t)boff;
  int m0 = blockIdx.y * 128, n0 = blockIdx.x * 128;
  if (CMODE == 1 && n0 > m0 + 127) return;
  int kmax = K;
  if (CMODE == 2) kmax = min(K, m0 + 128);

  __shared__ __align__(16) _Float16 As[128 * 32];
  __shared__ __align__(16) _Float16 Bs[128 * 32];

  int tid = threadIdx.x;
  int lane = tid & 63;
  int w = tid >> 6;
  int wm = ((tid >> 7) & 1) * 64;
  int wn = ((tid >> 6) & 1) * 64;
  int l15 = lane & 15, q4 = lane >> 4;

  int arow = w * 32;
  int lrow = lane >> 2, lcol = (lane & 3) * 8;
  const _Float16* Ag = Ab + (size_t)(m0 + arow + lrow) * lda + lcol;
  const _Float16* Bg = Bb + (size_t)(n0 + arow + lrow) * ldb + lcol;
  const _Float16* Ag2 = Ag + (size_t)16 * lda;
  const _Float16* Bg2 = Bg + (size_t)16 * ldb;
  _Float16* lA  = &As[arow * 32];
  _Float16* lA2 = &As[(arow + 16) * 32];
  _Float16* lB  = &Bs[arow * 32];
  _Float16* lB2 = &Bs[(arow + 16) * 32];

  floatx4 acc[4][4];
#pragma unroll
  for (int i = 0; i < 4; i++)
#pragma unroll
    for (int j = 0; j < 4; j++)
#pragma unroll
      for (int r = 0; r < 4; r++) acc[i][j][r] = 0.0f;

  for (int k0 = 0; k0 < kmax; k0 += 32) {
    gl_lds16(Ag + k0, lA);
    gl_lds16(Ag2 + k0, lA2);
    gl_lds16(Bg + k0, lB);
    gl_lds16(Bg2 + k0, lB2);
    __syncthreads();
    half8 af[4], bfr[4];
#pragma unroll
    for (int i = 0; i < 4; i++)
      af[i] = *(const half8*)(&As[(wm + i * 16 + l15) * 32 + q4 * 8]);
#pragma unroll
    for (int j = 0; j < 4; j++)
      bfr[j] = *(const half8*)(&Bs[(wn + j * 16 + l15) * 32 + q4 * 8]);
#pragma unroll
    for (int i = 0; i < 4; i++)
#pragma unroll
      for (int j = 0; j < 4; j++)
        acc[i][j] = __builtin_amdgcn_mfma_f32_16x16x32_f16(af[i], bfr[j], acc[i][j], 0, 0, 0);
    __syncthreads();
  }

#pragma unroll
  for (int i = 0; i < 4; i++) {
#pragma unroll
    for (int j = 0; j < 4; j++) {
#pragma unroll
      for (int r = 0; r < 4; r++) {
        int row = m0 + wm + i * 16 + q4 * 4 + r;
        int col = n0 + wn + j * 16 + l15;
        size_t o = (size_t)(coff + (long long)row * ldc + col);
        if (ADDRES) ((float*)Cv)[o] = acc[i][j][r] + Res[o];
        else        ((_Float16*)Cv)[o] = (_Float16)acc[i][j][r];
      }
    }
  }
}

// ---------------- RoPE on fused qkv (q at col 0, k at col D_) -------------------
__global__ void rope_kernel(_Float16* __restrict__ qkv, const void* __restrict__ pos) {
  int gid = blockIdx.x * 256 + threadIdx.x;   // BT_*H_*64 threads
  int d = gid & 63;
  int h = (gid >> 6) & 15;
  int bt = gid >> 10;
  const int* pi = (const int*)pos;
  long long pv = (pi[1] == 0 && pi[2] == 1) ? ((const long long*)pos)[bt]
                                            : (long long)pi[bt];
  float inv = exp2f((float)d * -0.2076205059304601f);  // 10000^(-d/64)
  float ang = (float)pv * inv;
  float s, c;
  sincosf(ang, &s, &c);
  size_t base = (size_t)bt * QKVLD_ + (size_t)h * HD_ + d;
  _Float16* q = qkv;
  _Float16* k = qkv + D_;
  float x1v = (float)q[base], x2v = (float)q[base + 64];
  q[base]      = (_Float16)(x1v * c - x2v * s);
  q[base + 64] = (_Float16)(x2v * c + x1v * s);
  x1v = (float)k[base]; x2v = (float)k[base + 64];
  k[base]      = (_Float16)(x1v * c - x2v * s);
  k[base + 64] = (_Float16)(x2v * c + x1v * s);
}

// ---------------- v[b][t][...] (ld stride) -> vt[(b*H+h)][d][t] -----------------
__global__ void vtrans_kernel(const _Float16* __restrict__ v, _Float16* __restrict__ vt,
                              int ld) {
  __shared__ _Float16 tile[32][33];
  int t0 = blockIdx.x * 32, d0 = blockIdx.y * 32, bh = blockIdx.z;
  int b = bh >> 4, h = bh & 15;
  int tx = threadIdx.x, ty = threadIdx.y;   // 32 x 8
  const _Float16* vb = v + (size_t)b * T_ * ld + (size_t)h * HD_;
#pragma unroll
  for (int r = 0; r < 32; r += 8)
    tile[ty + r][tx] = vb[(size_t)(t0 + ty + r) * ld + d0 + tx];
  __syncthreads();
  _Float16* vo = vt + ((size_t)bh * HD_ + d0) * T_ + t0;
#pragma unroll
  for (int r = 0; r < 32; r += 8)
    vo[(size_t)(ty + r) * T_ + tx] = tile[tx][ty + r];
}

// ---------------- causal softmax over one row of scores (in place) --------------
__global__ void softmax_kernel(_Float16* __restrict__ probs) {
  long long rowid = blockIdx.x;
  int i = (int)(rowid & (T_ - 1));
  _Float16* row = probs + (size_t)rowid * T_;
  int tid = threadIdx.x;
  int j0 = tid * 8;
  uint4 raw = *(const uint4*)(row + j0);
  const _Float16* ph = (const _Float16*)&raw;
  const float scale = 0.08838834764831845f;     // 1/sqrt(128)
  float vals[8];
  float mx = -1e30f;
#pragma unroll
  for (int l = 0; l < 8; l++) {
    float v = (j0 + l <= i) ? (float)ph[l] * scale : -1e30f;
    vals[l] = v; mx = fmaxf(mx, v);
  }
  __shared__ float red[256];
  red[tid] = mx; __syncthreads();
  for (int s = 128; s > 0; s >>= 1) { if (tid < s) red[tid] = fmaxf(red[tid], red[tid + s]); __syncthreads(); }
  float M = red[0]; __syncthreads();
  float se = 0.f;
#pragma unroll
  for (int l = 0; l < 8; l++) { float e = __expf(vals[l] - M); vals[l] = e; se += e; }
  red[tid] = se; __syncthreads();
  for (int s = 128; s > 0; s >>= 1) { if (tid < s) red[tid] += red[tid + s]; __syncthreads(); }
  float inv = 1.0f / red[0];
  _Float16 t[8] __attribute__((aligned(16)));
#pragma unroll
  for (int l = 0; l < 8; l++) t[l] = (j0 + l <= i) ? (_Float16)(vals[l] * inv) : (_Float16)0.f;
  *(uint4*)(row + j0) = *(const uint4*)t;
}

// ---------------- hu = silu(gate) * up  (written over gate) ---------------------
__global__ void silumul_kernel(_Float16* __restrict__ gate, const _Float16* __restrict__ up) {
  size_t idx = ((size_t)blockIdx.x * 256 + threadIdx.x) * 8;
  uint4 gr = *(const uint4*)(gate + idx);
  uint4 ur = *(const uint4*)(up + idx);
  const _Float16* gh = (const _Float16*)&gr;
  const _Float16* uh = (const _Float16*)&ur;
  _Float16 t[8] __attribute__((aligned(16)));
#pragma unroll
  for (int l = 0; l < 8; l++) {
    float x = (float)gh[l];
    float s = x / (1.0f + __expf(-x));
    t[l] = (_Float16)(s * (float)uh[l]);
  }
  *(uint4*)(gate + idx) = *(const uint4*)t;
}

// ================================================================================
extern "C" void kernel_launch(void* const* d_in, const int* in_sizes, int n_in,
                              void* d_out, int out_size, void* d_ws, size_t ws_size,
                              hipStream_t stream) {
  (void)in_sizes; (void)n_in; (void)out_size;
  const float* x   = (const float*)d_in[0];
  const void*  pos = d_in[1];
  const float* W[7] = { (const float*)d_in[2], (const float*)d_in[3],
                        (const float*)d_in[4], (const float*)d_in[5],
                        (const float*)d_in[6], (const float*)d_in[7],
                        (const float*)d_in[8] };              // q k v o g u d
  const float* g1  = (const float*)d_in[9];
  const float* g2  = (const float*)d_in[10];
  float* out = (float*)d_out;

  const int wk[7] = { D_, D_, D_, D_, D_, D_, FF_ };
  const int wn[7] = { D_, D_, D_, D_, FF_, FF_, D_ };

  char* p = (char*)d_ws;
  auto carve = [&](size_t bytes) { char* r = p; p += (bytes + 255) & ~(size_t)255; return r; };

  _Float16* probs = (_Float16*)carve((size_t)CH_ * T_ * T_ * 2);   // 64 MB; later: gate
  const size_t FLAT_NEED = (size_t)336 * 1024 * 1024;
  bool flat = ws_size >= FLAT_NEED;
  _Float16* w16[7];
  if (flat) {
    // q,k,v carved contiguously -> fused QKV weight matrix [6144][2048]
    for (int i = 0; i < 7; i++) w16[i] = (_Float16*)carve((size_t)wk[i] * wn[i] * 2);
  } else {
    _Float16* wslot = (_Float16*)carve((size_t)D_ * FF_ * 2);      // 32 MB slot
    w16[0] = wslot;
    w16[1] = wslot + (size_t)D_ * D_;
    w16[2] = wslot + (size_t)2 * D_ * D_;
    w16[3] = w16[4] = w16[5] = w16[6] = wslot;
  }
  _Float16* qkv = (_Float16*)carve((size_t)BT_ * QKVLD_ * 2);  // 48 MB
  _Float16* ob  = (_Float16*)carve((size_t)BT_ * D_ * 2);      // 16 MB (contig after qkv)
  _Float16* xn  = (_Float16*)carve((size_t)BT_ * D_ * 2);      // 16 MB; later: hb
  _Float16* vt  = (_Float16*)carve((size_t)BT_ * D_ * 2);      // 16 MB
  float*    x1  = (float*)   carve((size_t)BT_ * D_ * 4);      // 32 MB
  _Float16* gate = probs;        // 64 MB region, dead after PV
  _Float16* up   = qkv;          // spans qkv(48)+ob(16): both dead after Wo GEMM
  _Float16* hb   = xn;

  dim3 b328(32, 8);
  auto conv = [&](int i) {
    wconv_kernel<<<dim3(wn[i] / 32, wk[i] / 32), b328, 0, stream>>>(W[i], w16[i], wk[i], wn[i]);
  };
  if (flat) for (int i = 0; i < 7; i++) conv(i);

  // xn = rmsnorm(x, g1)
  rmsnorm_kernel<<<BT_, 256, 0, stream>>>(x, g1, xn);

  // fused qkv projection: [BT][6144] = xn @ [Wq;Wk;Wv]^T   (768 WGs)
  if (!flat) { conv(0); conv(1); conv(2); }
  gemm256<2, 0><<<dim3(QKVLD_ / 128, BT_ / 256), 512, 98304, stream>>>(
      xn, w16[0], qkv, nullptr, BT_, QKVLD_, D_, D_, D_, QKVLD_);

  // rope(q, k) in fused layout
  rope_kernel<<<(BT_ * H_ * 64) / 256, 256, 0, stream>>>(qkv, pos);

  // v transpose per head: vt[(b*H+h)][d][t]
  vtrans_kernel<<<dim3(T_ / 32, HD_ / 32, NP_), b328, 0, stream>>>(qkv + 2 * D_, vt, QKVLD_);

  // attention in chunks of CH_ (b,h) pairs (old 128x128 kernel: small K)
  for (int c = 0; c < NCH_; c++) {
    gemm_bt<1, 0, 2><<<dim3(T_ / 128, T_ / 128, CH_), 256, 0, stream>>>(
        qkv, qkv + D_, probs, nullptr, T_, T_, HD_, QKVLD_, QKVLD_, T_, c * CH_,
        (long long)T_ * QKVLD_, HD_, (long long)T_ * QKVLD_, HD_,
        (long long)T_ * T_, 0);
    softmax_kernel<<<CH_ * T_, 256, 0, stream>>>(probs);
    gemm_bt<2, 0, 1><<<dim3(1, T_ / 128, CH_), 256, 0, stream>>>(
        probs, vt, ob, nullptr, T_, HD_, T_, T_, T_, D_, c * CH_,
        (long long)T_ * T_, 0,
        16LL * HD_ * T_, (long long)HD_ * T_,
        (long long)T_ * D_, HD_);
  }

  // x1 = x + o @ Wo   (256 WGs)
  if (!flat) conv(3);
  gemm256<2, 1><<<dim3(D_ / 128, BT_ / 256), 512, 98304, stream>>>(
      ob, w16[3], x1, x, BT_, D_, D_, D_, D_, D_);

  // h = rmsnorm(x1, g2)
  rmsnorm_kernel<<<BT_, 256, 0, stream>>>(x1, g2, hb);

  // gate = h @ Wg ; up = h @ Wu   (512 WGs each)
  if (!flat) conv(4);
  gemm256<4, 0><<<dim3(FF_ / 256, BT_ / 256), 512, 131072, stream>>>(
      hb, w16[4], gate, nullptr, BT_, FF_, D_, D_, D_, FF_);
  if (!flat) conv(5);
  gemm256<4, 0><<<dim3(FF_ / 256, BT_ / 256), 512, 131072, stream>>>(
      hb, w16[5], up, nullptr, BT_, FF_, D_, D_, D_, FF_);

  // hu = silu(gate) * up  (in gate)
  silumul_kernel<<<(BT_ * FF_ / 8) / 256, 256, 0, stream>>>(gate, up);

  // out = x1 + hu @ Wd   (256 WGs)
  if (!flat) conv(6);
  gemm256<2, 1><<<dim3(D_ / 128, BT_ / 256), 512, 98304, stream>>>(
      gate, w16[6], out, x1, BT_, D_, FF_, FF_, FF_, D_);
}

// Round 2
// 1309.522 us; speedup vs baseline: 1.0692x; 1.0091x over previous
//
#include <hip/hip_runtime.h>
#include <cstdint>

#define D_  2048
#define H_  16
#define HD_ 128
#define FF_ 8192
#define T_  2048
#define B_  2
#define BT_ (B_*T_)
#define NP_ (B_*H_)        // 32 (b,h) pairs
#define CH_ 8              // pairs per attention chunk
#define NCH_ (NP_/CH_)     // 4 chunks
#define QKVLD_ (3*D_)      // fused qkv row stride (6144)

typedef __attribute__((ext_vector_type(8))) _Float16 half8;
typedef __attribute__((ext_vector_type(4))) float   floatx4;

// async global->LDS, 16B per lane; LDS dest = wave-uniform base + lane*16
__device__ __forceinline__ void gl_lds16(const void* g, void* l) {
  __builtin_amdgcn_global_load_lds(
      (const __attribute__((address_space(1))) void*)(uintptr_t)g,
      (__attribute__((address_space(3))) void*)(uintptr_t)l,
      16, 0, 0);
}

// ---------------- weight convert + transpose: W[K][N] f32 -> Wt[N][K] f16 ----
// 64 k-rows x 32 n-cols per block; packed uint stores (128B/row).
__global__ void wconv_kernel(const float* __restrict__ W, _Float16* __restrict__ Wt,
                             int K, int N) {
  __shared__ float tile[64][33];
  int n0 = blockIdx.x * 32, k0 = blockIdx.y * 64;
  int tx = threadIdx.x, ty = threadIdx.y;   // 32 x 8
#pragma unroll
  for (int r = 0; r < 64; r += 8)
    tile[ty + r][tx] = W[(size_t)(k0 + ty + r) * N + n0 + tx];
  __syncthreads();
#pragma unroll
  for (int r = 0; r < 32; r += 8) {
    float a = tile[tx * 2][ty + r], b = tile[tx * 2 + 1][ty + r];
    union { _Float16 h[2]; unsigned u; } cv;
    cv.h[0] = (_Float16)a; cv.h[1] = (_Float16)b;
    ((unsigned*)(Wt + (size_t)(n0 + ty + r) * K + k0))[tx] = cv.u;
  }
}

// ---------------- rmsnorm: fp32 row -> fp16 row --------------------------------
__global__ void rmsnorm_kernel(const float* __restrict__ x, const float* __restrict__ g,
                               _Float16* __restrict__ out) {
  int row = blockIdx.x, tid = threadIdx.x;
  const float4* xr = (const float4*)(x + (size_t)row * D_);
  float4 v1 = xr[tid], v2 = xr[tid + 256];
  float ss = v1.x*v1.x + v1.y*v1.y + v1.z*v1.z + v1.w*v1.w
           + v2.x*v2.x + v2.y*v2.y + v2.z*v2.z + v2.w*v2.w;
  __shared__ float red[256];
  red[tid] = ss; __syncthreads();
  for (int s = 128; s > 0; s >>= 1) { if (tid < s) red[tid] += red[tid + s]; __syncthreads(); }
  float rs = rsqrtf(red[0] * (1.0f / D_) + 1e-6f);
  float4 ga = ((const float4*)g)[tid], gb = ((const float4*)g)[tid + 256];
  _Float16* orow = out + (size_t)row * D_;
  _Float16 t[4] __attribute__((aligned(8)));
  t[0] = (_Float16)(v1.x * rs * ga.x);
  t[1] = (_Float16)(v1.y * rs * ga.y);
  t[2] = (_Float16)(v1.z * rs * ga.z);
  t[3] = (_Float16)(v1.w * rs * ga.w);
  *(uint2*)(orow + tid * 4) = *(const uint2*)t;
  t[0] = (_Float16)(v2.x * rs * gb.x);
  t[1] = (_Float16)(v2.y * rs * gb.y);
  t[2] = (_Float16)(v2.z * rs * gb.z);
  t[3] = (_Float16)(v2.w * rs * gb.w);
  *(uint2*)(orow + (tid + 256) * 4) = *(const uint2*)t;
}

// ================================================================================
// Deep-pipelined dense GEMM: C = A @ Bt^T.
// A: M x K f16 (lda), Bt: N x K f16 (ldb), C: M x N (ldc).
// BM=256, BN template; 512 threads = 8 waves arranged GM x GN;
// wave tile (256/GM) x (BN/GN). 4-slot LDS ring staged 3 K-tiles ahead with
// global_load_lds + counted vmcnt (never drained in steady state). Column
// swizzle (involution on 16B chunks) applied on the global source at stage
// time and on the ds_read address. XCD-bijective blockIdx remap (needs
// total WGs % 8 == 0). gridDim.z = split-K parts.
// OUTMODE: 0 -> C f16 = acc; 1 -> C f32 = acc + Res; 2 -> C f32 partial at
//          part bz (no Res).
// Requires M%256==0, N%BN==0, (K/gz)%32==0, K/gz>=128.
template<int GM, int GN, int BN, int OUTMODE>
__global__ __launch_bounds__(512, 2) void gemm256(
    const _Float16* __restrict__ A, const _Float16* __restrict__ Bt,
    void* __restrict__ Cv, const float* __restrict__ Res,
    int M, int N, int K, int lda, int ldb, int ldc)
{
  constexpr int WR  = 256 / GM;      // wave rows
  constexpr int WC  = BN / GN;       // wave cols
  constexpr int NI  = WR / 16;
  constexpr int NJc = WC / 16;
  constexpr int NIH = NI / 2;
  constexpr int RPT = 2 + BN / 128;  // stage rounds per K-tile
  constexpr int ASLOT = 256 * 32;
  constexpr int BSLOT = BN * 32;
  extern __shared__ _Float16 smem[];
  _Float16* As = smem;               // [4][ASLOT]
  _Float16* Bs = smem + 4 * ASLOT;   // [4][BSLOT]

  // XCD-bijective remap: physical wgid%8 = XCD; give each XCD a contiguous
  // x-fastest chunk of logical tiles (A-panels L2-resident per XCD).
  const int gx = gridDim.x, gy = gridDim.y, gz = gridDim.z;
  int pid = (blockIdx.z * gy + blockIdx.y) * gx + blockIdx.x;
  const int qch = (gx * gy * gz) >> 3;
  int lid = (pid & 7) * qch + (pid >> 3);
  const int bx = lid % gx; lid /= gx;
  const int by = lid % gy; const int bz = lid / gy;

  const int tid  = threadIdx.x;
  const int lane = tid & 63;
  const int w    = tid >> 6;          // 0..7
  const int wm   = w / GN;
  const int wn   = w % GN;
  const int l15  = lane & 15, q4 = lane >> 4;
  const int m0   = by * 256;
  const int n0   = bx * BN;
  const int KP   = K / gz;
  const int koff = bz * KP;
  const int NT   = KP >> 5;

  // staging: wave w covers rows [r*128 + w*16, +16), 4 x 16B chunks per row.
  const int srow = w * 16 + (lane >> 2);
  const int scol = (((lane & 3) ^ ((lane >> 3) & 3)) << 3);  // pre-swizzled col
  const _Float16* Ag = A  + (size_t)(m0 + srow) * lda + scol + koff;
  const _Float16* Bg = Bt + (size_t)(n0 + srow) * ldb + scol + koff;
  const int ldsW = w * 512;           // elems: wave base within a round

  // ds_read: logical chunk q4 lives at physical chunk q4 ^ ((row>>1)&3)
  const int chunk = ((q4 ^ ((l15 >> 1) & 3)) << 3);
  const int arow  = wm * WR + l15;
  const int brow  = wn * WC + l15;

  floatx4 acc[NI][NJc];
#pragma unroll
  for (int i = 0; i < NI; ++i)
#pragma unroll
    for (int j = 0; j < NJc; ++j)
#pragma unroll
      for (int r = 0; r < 4; ++r) acc[i][j][r] = 0.0f;

  auto stage = [&](int t, int r) {
    const int slot = t & 3;
    if (r < 2) {
      gl_lds16(Ag + (size_t)(r * 128) * lda + t * 32,
               As + slot * ASLOT + r * 4096 + ldsW);
    } else {
      if constexpr (BN == 256) {
        const int rb = r - 2;
        gl_lds16(Bg + (size_t)(rb * 128) * ldb + t * 32,
                 Bs + slot * BSLOT + rb * 4096 + ldsW);
      } else {
        gl_lds16(Bg + t * 32, Bs + slot * BSLOT + ldsW);
      }
    }
  };

  // prologue: stage tiles 0..2; ensure tile 0 landed (2*RPT still in flight).
  for (int t = 0; t < 3; ++t)
    for (int r = 0; r < RPT; ++r) stage(t, r);
  if constexpr (RPT == 4) asm volatile("s_waitcnt vmcnt(8)" ::: "memory");
  else                    asm volatile("s_waitcnt vmcnt(6)" ::: "memory");
  __builtin_amdgcn_s_barrier();

  half8 bf[NJc];
  for (int t = 0; t < NT; ++t) {
    const int slot = t & 3;
    const _Float16* aS = As + slot * ASLOT + arow * 32 + chunk;
    const _Float16* bS = Bs + slot * BSLOT + brow * 32 + chunk;
    const bool pf = (t + 3 < NT);

    // ---- phase 0: A rows [0, WR/2), all B frags ----
    half8 af[NIH];
#pragma unroll
    for (int i = 0; i < NIH; ++i) af[i] = *(const half8*)(aS + i * 16 * 32);
#pragma unroll
    for (int j = 0; j < NJc; ++j) bf[j] = *(const half8*)(bS + j * 16 * 32);
    if (pf) { stage(t + 3, 0); stage(t + 3, 1); }   // into slot (t-1)&3: safe
    __builtin_amdgcn_s_barrier();
    __builtin_amdgcn_s_setprio(1);
#pragma unroll
    for (int i = 0; i < NIH; ++i)
#pragma unroll
      for (int j = 0; j < NJc; ++j)
        acc[i][j] = __builtin_amdgcn_mfma_f32_16x16x32_f16(af[i], bf[j], acc[i][j], 0, 0, 0);
    __builtin_amdgcn_s_setprio(0);
    __builtin_amdgcn_s_barrier();

    // ---- phase 1: A rows [WR/2, WR) ----
#pragma unroll
    for (int i = 0; i < NIH; ++i) af[i] = *(const half8*)(aS + (WR / 2 + i * 16) * 32);
    if (pf) {
#pragma unroll
      for (int r = 2; r < RPT; ++r) stage(t + 3, r);
    }
    __builtin_amdgcn_s_barrier();
    __builtin_amdgcn_s_setprio(1);
#pragma unroll
    for (int i = 0; i < NIH; ++i)
#pragma unroll
      for (int j = 0; j < NJc; ++j)
        acc[NIH + i][j] = __builtin_amdgcn_mfma_f32_16x16x32_f16(af[i], bf[j], acc[NIH + i][j], 0, 0, 0);
    __builtin_amdgcn_s_setprio(0);

    // end-of-tile: tile t+1 must be fully landed before next iteration reads.
    if (pf) {
      if constexpr (RPT == 4) asm volatile("s_waitcnt vmcnt(8)" ::: "memory");
      else                    asm volatile("s_waitcnt vmcnt(6)" ::: "memory");
    } else if (t + 2 < NT) {
      if constexpr (RPT == 4) asm volatile("s_waitcnt vmcnt(4)" ::: "memory");
      else                    asm volatile("s_waitcnt vmcnt(3)" ::: "memory");
    } else {
      asm volatile("s_waitcnt vmcnt(0)" ::: "memory");
    }
    __builtin_amdgcn_s_barrier();
  }

  // epilogue: C/D layout col=lane&15, row=(lane>>4)*4+r
  const int crow0 = m0 + wm * WR + q4 * 4;
  const int ccol0 = n0 + wn * WC + l15;
#pragma unroll
  for (int i = 0; i < NI; ++i)
#pragma unroll
    for (int j = 0; j < NJc; ++j)
#pragma unroll
      for (int r = 0; r < 4; ++r) {
        size_t o = (size_t)(crow0 + i * 16 + r) * ldc + (ccol0 + j * 16);
        if constexpr (OUTMODE == 0)      ((_Float16*)Cv)[o] = (_Float16)acc[i][j][r];
        else if constexpr (OUTMODE == 1) ((float*)Cv)[o] = acc[i][j][r] + Res[o];
        else ((float*)Cv)[(size_t)bz * M * ldc + o] = acc[i][j][r];
      }
}

// ---------------- split-K reduce: out = p0 + p1 + res (all f32) -----------------
__global__ void addred_kernel(const float* __restrict__ parts, const float* __restrict__ res,
                              float* __restrict__ out) {
  size_t i = ((size_t)blockIdx.x * 256 + threadIdx.x) * 4;
  const size_t MN = (size_t)BT_ * D_;
  float4 a = *(const float4*)(parts + i);
  float4 b = *(const float4*)(parts + MN + i);
  float4 r = *(const float4*)(res + i);
  float4 o;
  o.x = a.x + b.x + r.x; o.y = a.y + b.y + r.y;
  o.z = a.z + b.z + r.z; o.w = a.w + b.w + r.w;
  *(float4*)(out + i) = o;
}

// ---------------- old 128x128 MFMA GEMM (attention scores / PV only) ------------
template<int CMODE, int ADDRES, int LOCALS>
__global__ __launch_bounds__(256, 3) void gemm_bt(
    const _Float16* __restrict__ A, const _Float16* __restrict__ Bt,
    void* __restrict__ Cv, const float* __restrict__ Res,
    int M, int N, int K, int lda, int ldb, int ldc, int pair0,
    long long sAd, long long sAm, long long sBd, long long sBm,
    long long sCd, long long sCm)
{
  // XCD-bijective remap (total WGs % 8 == 0): per-XCD pair locality.
  const int gx = gridDim.x, gy = gridDim.y;
  int pid = (blockIdx.z * gy + blockIdx.y) * gx + blockIdx.x;
  const int qch = (gx * gy * gridDim.z) >> 3;
  int lid = (pid & 7) * qch + (pid >> 3);
  const int bxx = lid % gx; lid /= gx;
  const int byy = lid % gy; const int bzz = lid / gy;

  int zl = bzz;
  int p = pair0 + zl;
  long long aoff = (LOCALS & 1) ? (long long)zl * sAd
                                : (long long)(p >> 4) * sAd + (long long)(p & 15) * sAm;
  long long boff = (long long)(p >> 4) * sBd + (long long)(p & 15) * sBm;
  long long coff = (LOCALS & 2) ? (long long)zl * sCd
                                : (long long)(p >> 4) * sCd + (long long)(p & 15) * sCm;
  const _Float16* Ab = A + (size_t)aoff;
  const _Float16* Bb = Bt + (size_t)boff;
  int m0 = byy * 128, n0 = bxx * 128;
  if (CMODE == 1 && n0 > m0 + 127) return;
  int kmax = K;
  if (CMODE == 2) kmax = min(K, m0 + 128);

  __shared__ __align__(16) _Float16 As[128 * 32];
  __shared__ __align__(16) _Float16 Bs[128 * 32];

  int tid = threadIdx.x;
  int lane = tid & 63;
  int w = tid >> 6;
  int wm = ((tid >> 7) & 1) * 64;
  int wn = ((tid >> 6) & 1) * 64;
  int l15 = lane & 15, q4 = lane >> 4;

  int arow = w * 32;
  int lrow = lane >> 2, lcol = (lane & 3) * 8;
  const _Float16* Ag = Ab + (size_t)(m0 + arow + lrow) * lda + lcol;
  const _Float16* Bg = Bb + (size_t)(n0 + arow + lrow) * ldb + lcol;
  const _Float16* Ag2 = Ag + (size_t)16 * lda;
  const _Float16* Bg2 = Bg + (size_t)16 * ldb;
  _Float16* lA  = &As[arow * 32];
  _Float16* lA2 = &As[(arow + 16) * 32];
  _Float16* lB  = &Bs[arow * 32];
  _Float16* lB2 = &Bs[(arow + 16) * 32];

  floatx4 acc[4][4];
#pragma unroll
  for (int i = 0; i < 4; i++)
#pragma unroll
    for (int j = 0; j < 4; j++)
#pragma unroll
      for (int r = 0; r < 4; r++) acc[i][j][r] = 0.0f;

  for (int k0 = 0; k0 < kmax; k0 += 32) {
    gl_lds16(Ag + k0, lA);
    gl_lds16(Ag2 + k0, lA2);
    gl_lds16(Bg + k0, lB);
    gl_lds16(Bg2 + k0, lB2);
    __syncthreads();
    half8 af[4], bfr[4];
#pragma unroll
    for (int i = 0; i < 4; i++)
      af[i] = *(const half8*)(&As[(wm + i * 16 + l15) * 32 + q4 * 8]);
#pragma unroll
    for (int j = 0; j < 4; j++)
      bfr[j] = *(const half8*)(&Bs[(wn + j * 16 + l15) * 32 + q4 * 8]);
#pragma unroll
    for (int i = 0; i < 4; i++)
#pragma unroll
      for (int j = 0; j < 4; j++)
        acc[i][j] = __builtin_amdgcn_mfma_f32_16x16x32_f16(af[i], bfr[j], acc[i][j], 0, 0, 0);
    __syncthreads();
  }

#pragma unroll
  for (int i = 0; i < 4; i++) {
#pragma unroll
    for (int j = 0; j < 4; j++) {
#pragma unroll
      for (int r = 0; r < 4; r++) {
        int row = m0 + wm + i * 16 + q4 * 4 + r;
        int col = n0 + wn + j * 16 + l15;
        size_t o = (size_t)(coff + (long long)row * ldc + col);
        if (ADDRES) ((float*)Cv)[o] = acc[i][j][r] + Res[o];
        else        ((_Float16*)Cv)[o] = (_Float16)acc[i][j][r];
      }
    }
  }
}

// ---------------- RoPE on fused qkv (q at col 0, k at col D_) -------------------
__global__ void rope_kernel(_Float16* __restrict__ qkv, const void* __restrict__ pos) {
  int gid = blockIdx.x * 256 + threadIdx.x;   // BT_*H_*64 threads
  int d = gid & 63;
  int h = (gid >> 6) & 15;
  int bt = gid >> 10;
  const int* pi = (const int*)pos;
  long long pv = (pi[1] == 0 && pi[2] == 1) ? ((const long long*)pos)[bt]
                                            : (long long)pi[bt];
  float inv = exp2f((float)d * -0.2076205059304601f);  // 10000^(-d/64)
  float ang = (float)pv * inv;
  float s, c;
  sincosf(ang, &s, &c);
  size_t base = (size_t)bt * QKVLD_ + (size_t)h * HD_ + d;
  _Float16* q = qkv;
  _Float16* k = qkv + D_;
  float x1v = (float)q[base], x2v = (float)q[base + 64];
  q[base]      = (_Float16)(x1v * c - x2v * s);
  q[base + 64] = (_Float16)(x2v * c + x1v * s);
  x1v = (float)k[base]; x2v = (float)k[base + 64];
  k[base]      = (_Float16)(x1v * c - x2v * s);
  k[base + 64] = (_Float16)(x2v * c + x1v * s);
}

// ---------------- v[b][t][...] (ld stride) -> vt[(b*H+h)][d][t] -----------------
__global__ void vtrans_kernel(const _Float16* __restrict__ v, _Float16* __restrict__ vt,
                              int ld) {
  __shared__ _Float16 tile[32][33];
  int t0 = blockIdx.x * 32, d0 = blockIdx.y * 32, bh = blockIdx.z;
  int b = bh >> 4, h = bh & 15;
  int tx = threadIdx.x, ty = threadIdx.y;   // 32 x 8
  const _Float16* vb = v + (size_t)b * T_ * ld + (size_t)h * HD_;
#pragma unroll
  for (int r = 0; r < 32; r += 8)
    tile[ty + r][tx] = vb[(size_t)(t0 + ty + r) * ld + d0 + tx];
  __syncthreads();
  _Float16* vo = vt + ((size_t)bh * HD_ + d0) * T_ + t0;
#pragma unroll
  for (int r = 0; r < 32; r += 8)
    vo[(size_t)(ty + r) * T_ + tx] = tile[tx][ty + r];
}

// ---------------- causal softmax over one row of scores (in place) --------------
__global__ void softmax_kernel(_Float16* __restrict__ probs) {
  long long rowid = blockIdx.x;
  int i = (int)(rowid & (T_ - 1));
  _Float16* row = probs + (size_t)rowid * T_;
  int tid = threadIdx.x;
  int j0 = tid * 8;
  uint4 raw = *(const uint4*)(row + j0);
  const _Float16* ph = (const _Float16*)&raw;
  const float scale = 0.08838834764831845f;     // 1/sqrt(128)
  float vals[8];
  float mx = -1e30f;
#pragma unroll
  for (int l = 0; l < 8; l++) {
    float v = (j0 + l <= i) ? (float)ph[l] * scale : -1e30f;
    vals[l] = v; mx = fmaxf(mx, v);
  }
  __shared__ float red[256];
  red[tid] = mx; __syncthreads();
  for (int s = 128; s > 0; s >>= 1) { if (tid < s) red[tid] = fmaxf(red[tid], red[tid + s]); __syncthreads(); }
  float M = red[0]; __syncthreads();
  float se = 0.f;
#pragma unroll
  for (int l = 0; l < 8; l++) { float e = __expf(vals[l] - M); vals[l] = e; se += e; }
  red[tid] = se; __syncthreads();
  for (int s = 128; s > 0; s >>= 1) { if (tid < s) red[tid] += red[tid + s]; __syncthreads(); }
  float inv = 1.0f / red[0];
  _Float16 t[8] __attribute__((aligned(16)));
#pragma unroll
  for (int l = 0; l < 8; l++) t[l] = (j0 + l <= i) ? (_Float16)(vals[l] * inv) : (_Float16)0.f;
  *(uint4*)(row + j0) = *(const uint4*)t;
}

// ---------------- hu = silu(gate) * up  (written over gate) ---------------------
__global__ void silumul_kernel(_Float16* __restrict__ gate, const _Float16* __restrict__ up) {
  size_t idx = ((size_t)blockIdx.x * 256 + threadIdx.x) * 8;
  uint4 gr = *(const uint4*)(gate + idx);
  uint4 ur = *(const uint4*)(up + idx);
  const _Float16* gh = (const _Float16*)&gr;
  const _Float16* uh = (const _Float16*)&ur;
  _Float16 t[8] __attribute__((aligned(16)));
#pragma unroll
  for (int l = 0; l < 8; l++) {
    float x = (float)gh[l];
    float s = x / (1.0f + __expf(-x));
    t[l] = (_Float16)(s * (float)uh[l]);
  }
  *(uint4*)(gate + idx) = *(const uint4*)t;
}

// ================================================================================
extern "C" void kernel_launch(void* const* d_in, const int* in_sizes, int n_in,
                              void* d_out, int out_size, void* d_ws, size_t ws_size,
                              hipStream_t stream) {
  (void)in_sizes; (void)n_in; (void)out_size;
  const float* x   = (const float*)d_in[0];
  const void*  pos = d_in[1];
  const float* W[7] = { (const float*)d_in[2], (const float*)d_in[3],
                        (const float*)d_in[4], (const float*)d_in[5],
                        (const float*)d_in[6], (const float*)d_in[7],
                        (const float*)d_in[8] };              // q k v o g u d
  const float* g1  = (const float*)d_in[9];
  const float* g2  = (const float*)d_in[10];
  float* out = (float*)d_out;

  const int wk[7] = { D_, D_, D_, D_, D_, D_, FF_ };
  const int wn[7] = { D_, D_, D_, D_, FF_, FF_, D_ };

  char* p = (char*)d_ws;
  auto carve = [&](size_t bytes) { char* r = p; p += (bytes + 255) & ~(size_t)255; return r; };

  _Float16* probs = (_Float16*)carve((size_t)CH_ * T_ * T_ * 2);   // 64 MB; later: gate
  const size_t FLAT_NEED = (size_t)336 * 1024 * 1024;
  bool flat = ws_size >= FLAT_NEED;
  _Float16* w16[7];
  if (flat) {
    // q,k,v carved contiguously -> fused QKV weight matrix [6144][2048]
    for (int i = 0; i < 7; i++) w16[i] = (_Float16*)carve((size_t)wk[i] * wn[i] * 2);
  } else {
    _Float16* wslot = (_Float16*)carve((size_t)D_ * FF_ * 2);      // 32 MB slot
    w16[0] = wslot;
    w16[1] = wslot + (size_t)D_ * D_;
    w16[2] = wslot + (size_t)2 * D_ * D_;
    w16[3] = w16[4] = w16[5] = w16[6] = wslot;
  }
  _Float16* qkv = (_Float16*)carve((size_t)BT_ * QKVLD_ * 2);  // 48 MB
  _Float16* ob  = (_Float16*)carve((size_t)BT_ * D_ * 2);      // 16 MB (contig after qkv)
  _Float16* xn  = (_Float16*)carve((size_t)BT_ * D_ * 2);      // 16 MB; later: hb
  _Float16* vt  = (_Float16*)carve((size_t)BT_ * D_ * 2);      // 16 MB
  float*    x1  = (float*)   carve((size_t)BT_ * D_ * 4);      // 32 MB
  _Float16* gate = probs;        // 64 MB region, dead after PV
  _Float16* up   = qkv;          // spans qkv(48)+ob(16): both dead after Wo GEMM
  _Float16* hb   = xn;
  float* parts = (float*)qkv;    // Wd split-K partials (2 x 32 MB); up dead by then

  dim3 b328(32, 8);
  auto conv = [&](int i) {
    wconv_kernel<<<dim3(wn[i] / 32, wk[i] / 64), b328, 0, stream>>>(W[i], w16[i], wk[i], wn[i]);
  };
  if (flat) for (int i = 0; i < 7; i++) conv(i);

  // xn = rmsnorm(x, g1)
  rmsnorm_kernel<<<BT_, 256, 0, stream>>>(x, g1, xn);

  // fused qkv projection: [BT][6144] = xn @ [Wq;Wk;Wv]^T   (384 WGs, NJ4)
  if (!flat) { conv(0); conv(1); conv(2); }
  gemm256<2, 4, 256, 0><<<dim3(QKVLD_ / 256, BT_ / 256, 1), 512, 131072, stream>>>(
      xn, w16[0], qkv, nullptr, BT_, QKVLD_, D_, D_, D_, QKVLD_);

  // rope(q, k) in fused layout
  rope_kernel<<<(BT_ * H_ * 64) / 256, 256, 0, stream>>>(qkv, pos);

  // v transpose per head: vt[(b*H+h)][d][t]
  vtrans_kernel<<<dim3(T_ / 32, HD_ / 32, NP_), b328, 0, stream>>>(qkv + 2 * D_, vt, QKVLD_);

  // attention in chunks of CH_ (b,h) pairs (old 128x128 kernel: small K)
  for (int c = 0; c < NCH_; c++) {
    gemm_bt<1, 0, 2><<<dim3(T_ / 128, T_ / 128, CH_), 256, 0, stream>>>(
        qkv, qkv + D_, probs, nullptr, T_, T_, HD_, QKVLD_, QKVLD_, T_, c * CH_,
        (long long)T_ * QKVLD_, HD_, (long long)T_ * QKVLD_, HD_,
        (long long)T_ * T_, 0);
    softmax_kernel<<<CH_ * T_, 256, 0, stream>>>(probs);
    gemm_bt<2, 0, 1><<<dim3(1, T_ / 128, CH_), 256, 0, stream>>>(
        probs, vt, ob, nullptr, T_, HD_, T_, T_, T_, D_, c * CH_,
        (long long)T_ * T_, 0,
        16LL * HD_ * T_, (long long)HD_ * T_,
        (long long)T_ * D_, HD_);
  }

  // x1 = x + o @ Wo   (256 WGs, 4Mx2N BN=128)
  if (!flat) conv(3);
  gemm256<4, 2, 128, 1><<<dim3(D_ / 128, BT_ / 256, 1), 512, 98304, stream>>>(
      ob, w16[3], x1, x, BT_, D_, D_, D_, D_, D_);

  // h = rmsnorm(x1, g2)
  rmsnorm_kernel<<<BT_, 256, 0, stream>>>(x1, g2, hb);

  // gate = h @ Wg ; up = h @ Wu   (512 WGs each, NJ4)
  if (!flat) conv(4);
  gemm256<2, 4, 256, 0><<<dim3(FF_ / 256, BT_ / 256, 1), 512, 131072, stream>>>(
      hb, w16[4], gate, nullptr, BT_, FF_, D_, D_, D_, FF_);
  if (!flat) conv(5);
  gemm256<2, 4, 256, 0><<<dim3(FF_ / 256, BT_ / 256, 1), 512, 131072, stream>>>(
      hb, w16[5], up, nullptr, BT_, FF_, D_, D_, D_, FF_);

  // hu = silu(gate) * up  (in gate)
  silumul_kernel<<<(BT_ * FF_ / 8) / 256, 256, 0, stream>>>(gate, up);

  // Wd split-K=2: partials = hu @ Wd (per half-K), then out = p0 + p1 + x1
  if (!flat) conv(6);
  gemm256<2, 4, 256, 2><<<dim3(D_ / 256, BT_ / 256, 2), 512, 131072, stream>>>(
      gate, w16[6], parts, nullptr, BT_, D_, FF_, FF_, FF_, D_);
  addred_kernel<<<(BT_ * D_ / 4) / 256, 256, 0, stream>>>(parts, x1, out);
}

// Round 3
// 1278.356 us; speedup vs baseline: 1.0952x; 1.0244x over previous
//
#include <hip/hip_runtime.h>
#include <cstdint>

#define D_  2048
#define H_  16
#define HD_ 128
#define FF_ 8192
#define T_  2048
#define B_  2
#define BT_ (B_*T_)
#define NP_ (B_*H_)        // 32 (b,h) pairs
#define CH_ 8              // pairs per attention chunk
#define NCH_ (NP_/CH_)     // 4 chunks
#define QKVLD_ (3*D_)      // fused qkv row stride (6144)

typedef __attribute__((ext_vector_type(8))) _Float16 half8;
typedef __attribute__((ext_vector_type(4))) float   floatx4;

// async global->LDS, 16B per lane; LDS dest = wave-uniform base + lane*16
__device__ __forceinline__ void gl_lds16(const void* g, void* l) {
  __builtin_amdgcn_global_load_lds(
      (const __attribute__((address_space(1))) void*)(uintptr_t)g,
      (__attribute__((address_space(3))) void*)(uintptr_t)l,
      16, 0, 0);
}

// ---------------- weight convert + transpose: W[K][N] f32 -> Wt[N][K] f16 ----
// 64 k-rows x 32 n-cols per block; packed uint stores (128B/row).
__global__ void wconv_kernel(const float* __restrict__ W, _Float16* __restrict__ Wt,
                             int K, int N) {
  __shared__ float tile[64][33];
  int n0 = blockIdx.x * 32, k0 = blockIdx.y * 64;
  int tx = threadIdx.x, ty = threadIdx.y;   // 32 x 8
#pragma unroll
  for (int r = 0; r < 64; r += 8)
    tile[ty + r][tx] = W[(size_t)(k0 + ty + r) * N + n0 + tx];
  __syncthreads();
#pragma unroll
  for (int r = 0; r < 32; r += 8) {
    float a = tile[tx * 2][ty + r], b = tile[tx * 2 + 1][ty + r];
    union { _Float16 h[2]; unsigned u; } cv;
    cv.h[0] = (_Float16)a; cv.h[1] = (_Float16)b;
    ((unsigned*)(Wt + (size_t)(n0 + ty + r) * K + k0))[tx] = cv.u;
  }
}

// ---------------- rmsnorm: fp32 row -> fp16 row --------------------------------
__global__ void rmsnorm_kernel(const float* __restrict__ x, const float* __restrict__ g,
                               _Float16* __restrict__ out) {
  int row = blockIdx.x, tid = threadIdx.x;
  const float4* xr = (const float4*)(x + (size_t)row * D_);
  float4 v1 = xr[tid], v2 = xr[tid + 256];
  float ss = v1.x*v1.x + v1.y*v1.y + v1.z*v1.z + v1.w*v1.w
           + v2.x*v2.x + v2.y*v2.y + v2.z*v2.z + v2.w*v2.w;
  __shared__ float red[256];
  red[tid] = ss; __syncthreads();
  for (int s = 128; s > 0; s >>= 1) { if (tid < s) red[tid] += red[tid + s]; __syncthreads(); }
  float rs = rsqrtf(red[0] * (1.0f / D_) + 1e-6f);
  float4 ga = ((const float4*)g)[tid], gb = ((const float4*)g)[tid + 256];
  _Float16* orow = out + (size_t)row * D_;
  _Float16 t[4] __attribute__((aligned(8)));
  t[0] = (_Float16)(v1.x * rs * ga.x);
  t[1] = (_Float16)(v1.y * rs * ga.y);
  t[2] = (_Float16)(v1.z * rs * ga.z);
  t[3] = (_Float16)(v1.w * rs * ga.w);
  *(uint2*)(orow + tid * 4) = *(const uint2*)t;
  t[0] = (_Float16)(v2.x * rs * gb.x);
  t[1] = (_Float16)(v2.y * rs * gb.y);
  t[2] = (_Float16)(v2.z * rs * gb.z);
  t[3] = (_Float16)(v2.w * rs * gb.w);
  *(uint2*)(orow + (tid + 256) * 4) = *(const uint2*)t;
}

// ================================================================================
// Deep-pipelined dense GEMM: C = A @ Bt^T.
// A: M x K f16 (lda), Bt: N x K f16 (ldb), C: M x N (ldc).
// BM=256, BN template; 512 threads = 8 waves arranged GM x GN;
// wave tile (256/GM) x (BN/GN). 4-slot LDS ring staged 3 K-tiles ahead with
// global_load_lds + counted vmcnt. ONE barrier per K-tile; B fragments
// register-double-buffered (prefetched one tile ahead), A fragments read at
// tile top and consumed i-outer so only the first read's latency is exposed;
// all 32 MFMAs per tile form one cluster overlapped with the next tile's
// ds_reads. Race ledger: lgkmcnt(0) before each barrier drains all frag
// reads of slot (t-1)&3 before any wave's stage(t+3) (issued post-barrier)
// can overwrite it; vmcnt(RPT)+barrier guarantees tile t+1 landed before
// prefetchB(t+1). Column swizzle on global source + ds_read address.
// XCD-bijective blockIdx remap (total WGs % 8 == 0). gridDim.z = split-K.
// OUTMODE: 0 -> C f16 = acc; 1 -> C f32 = acc + Res; 2 -> C f32 partial.
// Requires M%256==0, N%BN==0, (K/gz)%32==0, K/(32*gz) even and >= 4.
template<int GM, int GN, int BN, int OUTMODE>
__global__ __launch_bounds__(512, 2) void gemm256(
    const _Float16* __restrict__ A, const _Float16* __restrict__ Bt,
    void* __restrict__ Cv, const float* __restrict__ Res,
    int M, int N, int K, int lda, int ldb, int ldc)
{
  constexpr int WR  = 256 / GM;      // wave rows
  constexpr int WC  = BN / GN;       // wave cols
  constexpr int NI  = WR / 16;
  constexpr int NJc = WC / 16;
  constexpr int RPT = 2 + BN / 128;  // stage rounds per K-tile
  constexpr int ASLOT = 256 * 32;
  constexpr int BSLOT = BN * 32;
  extern __shared__ _Float16 smem[];
  _Float16* As = smem;               // [4][ASLOT]
  _Float16* Bs = smem + 4 * ASLOT;   // [4][BSLOT]

  // XCD-bijective remap: physical wgid%8 = XCD; give each XCD a contiguous
  // x-fastest chunk of logical tiles (A-panels L2-resident per XCD).
  const int gx = gridDim.x, gy = gridDim.y, gz = gridDim.z;
  int pid = (blockIdx.z * gy + blockIdx.y) * gx + blockIdx.x;
  const int qch = (gx * gy * gz) >> 3;
  int lid = (pid & 7) * qch + (pid >> 3);
  const int bx = lid % gx; lid /= gx;
  const int by = lid % gy; const int bz = lid / gy;

  const int tid  = threadIdx.x;
  const int lane = tid & 63;
  const int w    = tid >> 6;          // 0..7
  const int wm   = w / GN;
  const int wn   = w % GN;
  const int l15  = lane & 15, q4 = lane >> 4;
  const int m0   = by * 256;
  const int n0   = bx * BN;
  const int KP   = K / gz;
  const int koff = bz * KP;
  const int NT   = KP >> 5;

  // staging: wave w covers rows [r*128 + w*16, +16), 4 x 16B chunks per row.
  const int srow = w * 16 + (lane >> 2);
  const int scol = (((lane & 3) ^ ((lane >> 3) & 3)) << 3);  // pre-swizzled col
  const _Float16* Ag = A  + (size_t)(m0 + srow) * lda + scol + koff;
  const _Float16* Bg = Bt + (size_t)(n0 + srow) * ldb + scol + koff;
  const int ldsW = w * 512;           // elems: wave base within a round

  // ds_read: logical chunk q4 lives at physical chunk q4 ^ ((row>>1)&3)
  const int chunk = ((q4 ^ ((l15 >> 1) & 3)) << 3);
  const int arow  = wm * WR + l15;
  const int brow  = wn * WC + l15;

  floatx4 acc[NI][NJc];
#pragma unroll
  for (int i = 0; i < NI; ++i)
#pragma unroll
    for (int j = 0; j < NJc; ++j)
#pragma unroll
      for (int r = 0; r < 4; ++r) acc[i][j][r] = 0.0f;

  auto stage = [&](int t, int r) {
    const int slot = t & 3;
    if (r < 2) {
      gl_lds16(Ag + (size_t)(r * 128) * lda + t * 32,
               As + slot * ASLOT + r * 4096 + ldsW);
    } else {
      if constexpr (BN == 256) {
        const int rb = r - 2;
        gl_lds16(Bg + (size_t)(rb * 128) * ldb + t * 32,
                 Bs + slot * BSLOT + rb * 4096 + ldsW);
      } else {
        gl_lds16(Bg + t * 32, Bs + slot * BSLOT + ldsW);
      }
    }
  };
  auto readB = [&](int t, half8 (&bf)[NJc]) {
    const int slot = t & 3;
    const _Float16* bS = Bs + slot * BSLOT + brow * 32 + chunk;
#pragma unroll
    for (int j = 0; j < NJc; ++j) bf[j] = *(const half8*)(bS + j * 16 * 32);
  };

  // one K-tile section: [vmcnt; lgkmcnt(0); barrier; stage(t+3); readA(t);
  //                      prefetchB(t+1) -> bP; MFMA(t) on af x bU]
  auto section = [&](int t, half8 (&bU)[NJc], half8 (&bP)[NJc]) {
    if (t + 3 <= NT) {
      if constexpr (RPT == 4) asm volatile("s_waitcnt vmcnt(4)" ::: "memory");
      else                    asm volatile("s_waitcnt vmcnt(3)" ::: "memory");
    } else {
      asm volatile("s_waitcnt vmcnt(0)" ::: "memory");
    }
    asm volatile("s_waitcnt lgkmcnt(0)" ::: "memory");
    __builtin_amdgcn_s_barrier();
    if (t + 3 < NT) {
#pragma unroll
      for (int r = 0; r < RPT; ++r) stage(t + 3, r);
    }
    const int slot = t & 3;
    const _Float16* aS = As + slot * ASLOT + arow * 32 + chunk;
    half8 af[NI];
#pragma unroll
    for (int i = 0; i < NI; ++i) af[i] = *(const half8*)(aS + i * 16 * 32);
    if (t + 1 < NT) readB(t + 1, bP);
    __builtin_amdgcn_s_setprio(1);
#pragma unroll
    for (int i = 0; i < NI; ++i)
#pragma unroll
      for (int j = 0; j < NJc; ++j)
        acc[i][j] = __builtin_amdgcn_mfma_f32_16x16x32_f16(af[i], bU[j], acc[i][j], 0, 0, 0);
    __builtin_amdgcn_s_setprio(0);
  };

  // prologue: stage tiles 0..2; ensure tile 0 landed (2*RPT still in flight);
  // prefetch B(0) into set 0.
  for (int t = 0; t < 3; ++t)
    for (int r = 0; r < RPT; ++r) stage(t, r);
  if constexpr (RPT == 4) asm volatile("s_waitcnt vmcnt(8)" ::: "memory");
  else                    asm volatile("s_waitcnt vmcnt(6)" ::: "memory");
  __builtin_amdgcn_s_barrier();
  half8 bf0[NJc], bf1[NJc];
  readB(0, bf0);

  for (int t = 0; t < NT; t += 2) {
    section(t,     bf0, bf1);
    section(t + 1, bf1, bf0);
  }

  // epilogue: C/D layout col=lane&15, row=(lane>>4)*4+r
  const int crow0 = m0 + wm * WR + q4 * 4;
  const int ccol0 = n0 + wn * WC + l15;
#pragma unroll
  for (int i = 0; i < NI; ++i)
#pragma unroll
    for (int j = 0; j < NJc; ++j)
#pragma unroll
      for (int r = 0; r < 4; ++r) {
        size_t o = (size_t)(crow0 + i * 16 + r) * ldc + (ccol0 + j * 16);
        if constexpr (OUTMODE == 0)      ((_Float16*)Cv)[o] = (_Float16)acc[i][j][r];
        else if constexpr (OUTMODE == 1) ((float*)Cv)[o] = acc[i][j][r] + Res[o];
        else ((float*)Cv)[(size_t)bz * M * ldc + o] = acc[i][j][r];
      }
}

// ---------------- split-K reduce: out = p0 + p1 + res (all f32) -----------------
__global__ void addred_kernel(const float* __restrict__ parts, const float* __restrict__ res,
                              float* __restrict__ out) {
  size_t i = ((size_t)blockIdx.x * 256 + threadIdx.x) * 4;
  const size_t MN = (size_t)BT_ * D_;
  float4 a = *(const float4*)(parts + i);
  float4 b = *(const float4*)(parts + MN + i);
  float4 r = *(const float4*)(res + i);
  float4 o;
  o.x = a.x + b.x + r.x; o.y = a.y + b.y + r.y;
  o.z = a.z + b.z + r.z; o.w = a.w + b.w + r.w;
  *(float4*)(out + i) = o;
}

// ---------------- old 128x128 MFMA GEMM (attention scores / PV only) ------------
template<int CMODE, int ADDRES, int LOCALS>
__global__ __launch_bounds__(256, 3) void gemm_bt(
    const _Float16* __restrict__ A, const _Float16* __restrict__ Bt,
    void* __restrict__ Cv, const float* __restrict__ Res,
    int M, int N, int K, int lda, int ldb, int ldc, int pair0,
    long long sAd, long long sAm, long long sBd, long long sBm,
    long long sCd, long long sCm)
{
  // XCD-bijective remap (total WGs % 8 == 0): per-XCD pair locality.
  const int gx = gridDim.x, gy = gridDim.y;
  int pid = (blockIdx.z * gy + blockIdx.y) * gx + blockIdx.x;
  const int qch = (gx * gy * gridDim.z) >> 3;
  int lid = (pid & 7) * qch + (pid >> 3);
  const int bxx = lid % gx; lid /= gx;
  const int byy = lid % gy; const int bzz = lid / gy;

  int zl = bzz;
  int p = pair0 + zl;
  long long aoff = (LOCALS & 1) ? (long long)zl * sAd
                                : (long long)(p >> 4) * sAd + (long long)(p & 15) * sAm;
  long long boff = (long long)(p >> 4) * sBd + (long long)(p & 15) * sBm;
  long long coff = (LOCALS & 2) ? (long long)zl * sCd
                                : (long long)(p >> 4) * sCd + (long long)(p & 15) * sCm;
  const _Float16* Ab = A + (size_t)aoff;
  const _Float16* Bb = Bt + (size_t)boff;
  int m0 = byy * 128, n0 = bxx * 128;
  if (CMODE == 1 && n0 > m0 + 127) return;
  int kmax = K;
  if (CMODE == 2) kmax = min(K, m0 + 128);

  __shared__ __align__(16) _Float16 As[128 * 32];
  __shared__ __align__(16) _Float16 Bs[128 * 32];

  int tid = threadIdx.x;
  int lane = tid & 63;
  int w = tid >> 6;
  int wm = ((tid >> 7) & 1) * 64;
  int wn = ((tid >> 6) & 1) * 64;
  int l15 = lane & 15, q4 = lane >> 4;

  int arow = w * 32;
  int lrow = lane >> 2, lcol = (lane & 3) * 8;
  const _Float16* Ag = Ab + (size_t)(m0 + arow + lrow) * lda + lcol;
  const _Float16* Bg = Bb + (size_t)(n0 + arow + lrow) * ldb + lcol;
  const _Float16* Ag2 = Ag + (size_t)16 * lda;
  const _Float16* Bg2 = Bg + (size_t)16 * ldb;
  _Float16* lA  = &As[arow * 32];
  _Float16* lA2 = &As[(arow + 16) * 32];
  _Float16* lB  = &Bs[arow * 32];
  _Float16* lB2 = &Bs[(arow + 16) * 32];

  floatx4 acc[4][4];
#pragma unroll
  for (int i = 0; i < 4; i++)
#pragma unroll
    for (int j = 0; j < 4; j++)
#pragma unroll
      for (int r = 0; r < 4; r++) acc[i][j][r] = 0.0f;

  for (int k0 = 0; k0 < kmax; k0 += 32) {
    gl_lds16(Ag + k0, lA);
    gl_lds16(Ag2 + k0, lA2);
    gl_lds16(Bg + k0, lB);
    gl_lds16(Bg2 + k0, lB2);
    __syncthreads();
    half8 af[4], bfr[4];
#pragma unroll
    for (int i = 0; i < 4; i++)
      af[i] = *(const half8*)(&As[(wm + i * 16 + l15) * 32 + q4 * 8]);
#pragma unroll
    for (int j = 0; j < 4; j++)
      bfr[j] = *(const half8*)(&Bs[(wn + j * 16 + l15) * 32 + q4 * 8]);
#pragma unroll
    for (int i = 0; i < 4; i++)
#pragma unroll
      for (int j = 0; j < 4; j++)
        acc[i][j] = __builtin_amdgcn_mfma_f32_16x16x32_f16(af[i], bfr[j], acc[i][j], 0, 0, 0);
    __syncthreads();
  }

#pragma unroll
  for (int i = 0; i < 4; i++) {
#pragma unroll
    for (int j = 0; j < 4; j++) {
#pragma unroll
      for (int r = 0; r < 4; r++) {
        int row = m0 + wm + i * 16 + q4 * 4 + r;
        int col = n0 + wn + j * 16 + l15;
        size_t o = (size_t)(coff + (long long)row * ldc + col);
        if (ADDRES) ((float*)Cv)[o] = acc[i][j][r] + Res[o];
        else        ((_Float16*)Cv)[o] = (_Float16)acc[i][j][r];
      }
    }
  }
}

// ---------------- RoPE on fused qkv (q at col 0, k at col D_) -------------------
__global__ void rope_kernel(_Float16* __restrict__ qkv, const void* __restrict__ pos) {
  int gid = blockIdx.x * 256 + threadIdx.x;   // BT_*H_*64 threads
  int d = gid & 63;
  int h = (gid >> 6) & 15;
  int bt = gid >> 10;
  const int* pi = (const int*)pos;
  long long pv = (pi[1] == 0 && pi[2] == 1) ? ((const long long*)pos)[bt]
                                            : (long long)pi[bt];
  float inv = exp2f((float)d * -0.2076205059304601f);  // 10000^(-d/64)
  float ang = (float)pv * inv;
  float s, c;
  sincosf(ang, &s, &c);
  size_t base = (size_t)bt * QKVLD_ + (size_t)h * HD_ + d;
  _Float16* q = qkv;
  _Float16* k = qkv + D_;
  float x1v = (float)q[base], x2v = (float)q[base + 64];
  q[base]      = (_Float16)(x1v * c - x2v * s);
  q[base + 64] = (_Float16)(x2v * c + x1v * s);
  x1v = (float)k[base]; x2v = (float)k[base + 64];
  k[base]      = (_Float16)(x1v * c - x2v * s);
  k[base + 64] = (_Float16)(x2v * c + x1v * s);
}

// ---------------- v[b][t][...] (ld stride) -> vt[(b*H+h)][d][t] -----------------
__global__ void vtrans_kernel(const _Float16* __restrict__ v, _Float16* __restrict__ vt,
                              int ld) {
  __shared__ _Float16 tile[32][33];
  int t0 = blockIdx.x * 32, d0 = blockIdx.y * 32, bh = blockIdx.z;
  int b = bh >> 4, h = bh & 15;
  int tx = threadIdx.x, ty = threadIdx.y;   // 32 x 8
  const _Float16* vb = v + (size_t)b * T_ * ld + (size_t)h * HD_;
#pragma unroll
  for (int r = 0; r < 32; r += 8)
    tile[ty + r][tx] = vb[(size_t)(t0 + ty + r) * ld + d0 + tx];
  __syncthreads();
  _Float16* vo = vt + ((size_t)bh * HD_ + d0) * T_ + t0;
#pragma unroll
  for (int r = 0; r < 32; r += 8)
    vo[(size_t)(ty + r) * T_ + tx] = tile[tx][ty + r];
}

// ---------------- causal softmax over one row of scores (in place) --------------
__global__ void softmax_kernel(_Float16* __restrict__ probs) {
  long long rowid = blockIdx.x;
  int i = (int)(rowid & (T_ - 1));
  _Float16* row = probs + (size_t)rowid * T_;
  int tid = threadIdx.x;
  int j0 = tid * 8;
  uint4 raw = *(const uint4*)(row + j0);
  const _Float16* ph = (const _Float16*)&raw;
  const float scale = 0.08838834764831845f;     // 1/sqrt(128)
  float vals[8];
  float mx = -1e30f;
#pragma unroll
  for (int l = 0; l < 8; l++) {
    float v = (j0 + l <= i) ? (float)ph[l] * scale : -1e30f;
    vals[l] = v; mx = fmaxf(mx, v);
  }
  __shared__ float red[256];
  red[tid] = mx; __syncthreads();
  for (int s = 128; s > 0; s >>= 1) { if (tid < s) red[tid] = fmaxf(red[tid], red[tid + s]); __syncthreads(); }
  float M = red[0]; __syncthreads();
  float se = 0.f;
#pragma unroll
  for (int l = 0; l < 8; l++) { float e = __expf(vals[l] - M); vals[l] = e; se += e; }
  red[tid] = se; __syncthreads();
  for (int s = 128; s > 0; s >>= 1) { if (tid < s) red[tid] += red[tid + s]; __syncthreads(); }
  float inv = 1.0f / red[0];
  _Float16 t[8] __attribute__((aligned(16)));
#pragma unroll
  for (int l = 0; l < 8; l++) t[l] = (j0 + l <= i) ? (_Float16)(vals[l] * inv) : (_Float16)0.f;
  *(uint4*)(row + j0) = *(const uint4*)t;
}

// ---------------- hu = silu(gate) * up  (written over gate) ---------------------
__global__ void silumul_kernel(_Float16* __restrict__ gate, const _Float16* __restrict__ up) {
  size_t idx = ((size_t)blockIdx.x * 256 + threadIdx.x) * 8;
  uint4 gr = *(const uint4*)(gate + idx);
  uint4 ur = *(const uint4*)(up + idx);
  const _Float16* gh = (const _Float16*)&gr;
  const _Float16* uh = (const _Float16*)&ur;
  _Float16 t[8] __attribute__((aligned(16)));
#pragma unroll
  for (int l = 0; l < 8; l++) {
    float x = (float)gh[l];
    float s = x / (1.0f + __expf(-x));
    t[l] = (_Float16)(s * (float)uh[l]);
  }
  *(uint4*)(gate + idx) = *(const uint4*)t;
}

// ================================================================================
extern "C" void kernel_launch(void* const* d_in, const int* in_sizes, int n_in,
                              void* d_out, int out_size, void* d_ws, size_t ws_size,
                              hipStream_t stream) {
  (void)in_sizes; (void)n_in; (void)out_size;
  const float* x   = (const float*)d_in[0];
  const void*  pos = d_in[1];
  const float* W[7] = { (const float*)d_in[2], (const float*)d_in[3],
                        (const float*)d_in[4], (const float*)d_in[5],
                        (const float*)d_in[6], (const float*)d_in[7],
                        (const float*)d_in[8] };              // q k v o g u d
  const float* g1  = (const float*)d_in[9];
  const float* g2  = (const float*)d_in[10];
  float* out = (float*)d_out;

  const int wk[7] = { D_, D_, D_, D_, D_, D_, FF_ };
  const int wn[7] = { D_, D_, D_, D_, FF_, FF_, D_ };

  char* p = (char*)d_ws;
  auto carve = [&](size_t bytes) { char* r = p; p += (bytes + 255) & ~(size_t)255; return r; };

  _Float16* probs = (_Float16*)carve((size_t)CH_ * T_ * T_ * 2);   // 64 MB; later: gate
  const size_t FLAT_NEED = (size_t)336 * 1024 * 1024;
  bool flat = ws_size >= FLAT_NEED;
  _Float16* w16[7];
  if (flat) {
    // q,k,v carved contiguously -> fused QKV weight matrix [6144][2048]
    for (int i = 0; i < 7; i++) w16[i] = (_Float16*)carve((size_t)wk[i] * wn[i] * 2);
  } else {
    _Float16* wslot = (_Float16*)carve((size_t)D_ * FF_ * 2);      // 32 MB slot
    w16[0] = wslot;
    w16[1] = wslot + (size_t)D_ * D_;
    w16[2] = wslot + (size_t)2 * D_ * D_;
    w16[3] = w16[4] = w16[5] = w16[6] = wslot;
  }
  _Float16* qkv = (_Float16*)carve((size_t)BT_ * QKVLD_ * 2);  // 48 MB
  _Float16* ob  = (_Float16*)carve((size_t)BT_ * D_ * 2);      // 16 MB (contig after qkv)
  _Float16* xn  = (_Float16*)carve((size_t)BT_ * D_ * 2);      // 16 MB; later: hb
  _Float16* vt  = (_Float16*)carve((size_t)BT_ * D_ * 2);      // 16 MB
  float*    x1  = (float*)   carve((size_t)BT_ * D_ * 4);      // 32 MB
  _Float16* gate = probs;        // 64 MB region, dead after PV
  _Float16* up   = qkv;          // spans qkv(48)+ob(16): both dead after Wo GEMM
  _Float16* hb   = xn;
  float* parts = (float*)qkv;    // Wd split-K partials (2 x 32 MB); up dead by then

  dim3 b328(32, 8);
  auto conv = [&](int i) {
    wconv_kernel<<<dim3(wn[i] / 32, wk[i] / 64), b328, 0, stream>>>(W[i], w16[i], wk[i], wn[i]);
  };
  if (flat) for (int i = 0; i < 7; i++) conv(i);

  // xn = rmsnorm(x, g1)
  rmsnorm_kernel<<<BT_, 256, 0, stream>>>(x, g1, xn);

  // fused qkv projection: [BT][6144] = xn @ [Wq;Wk;Wv]^T   (384 WGs, NJ4)
  if (!flat) { conv(0); conv(1); conv(2); }
  gemm256<2, 4, 256, 0><<<dim3(QKVLD_ / 256, BT_ / 256, 1), 512, 131072, stream>>>(
      xn, w16[0], qkv, nullptr, BT_, QKVLD_, D_, D_, D_, QKVLD_);

  // rope(q, k) in fused layout
  rope_kernel<<<(BT_ * H_ * 64) / 256, 256, 0, stream>>>(qkv, pos);

  // v transpose per head: vt[(b*H+h)][d][t]
  vtrans_kernel<<<dim3(T_ / 32, HD_ / 32, NP_), b328, 0, stream>>>(qkv + 2 * D_, vt, QKVLD_);

  // attention in chunks of CH_ (b,h) pairs (old 128x128 kernel: small K)
  for (int c = 0; c < NCH_; c++) {
    gemm_bt<1, 0, 2><<<dim3(T_ / 128, T_ / 128, CH_), 256, 0, stream>>>(
        qkv, qkv + D_, probs, nullptr, T_, T_, HD_, QKVLD_, QKVLD_, T_, c * CH_,
        (long long)T_ * QKVLD_, HD_, (long long)T_ * QKVLD_, HD_,
        (long long)T_ * T_, 0);
    softmax_kernel<<<CH_ * T_, 256, 0, stream>>>(probs);
    gemm_bt<2, 0, 1><<<dim3(1, T_ / 128, CH_), 256, 0, stream>>>(
        probs, vt, ob, nullptr, T_, HD_, T_, T_, T_, D_, c * CH_,
        (long long)T_ * T_, 0,
        16LL * HD_ * T_, (long long)HD_ * T_,
        (long long)T_ * D_, HD_);
  }

  // x1 = x + o @ Wo   (256 WGs, 4Mx2N BN=128)
  if (!flat) conv(3);
  gemm256<4, 2, 128, 1><<<dim3(D_ / 128, BT_ / 256, 1), 512, 98304, stream>>>(
      ob, w16[3], x1, x, BT_, D_, D_, D_, D_, D_);

  // h = rmsnorm(x1, g2)
  rmsnorm_kernel<<<BT_, 256, 0, stream>>>(x1, g2, hb);

  // gate = h @ Wg ; up = h @ Wu   (512 WGs each, NJ4)
  if (!flat) conv(4);
  gemm256<2, 4, 256, 0><<<dim3(FF_ / 256, BT_ / 256, 1), 512, 131072, stream>>>(
      hb, w16[4], gate, nullptr, BT_, FF_, D_, D_, D_, FF_);
  if (!flat) conv(5);
  gemm256<2, 4, 256, 0><<<dim3(FF_ / 256, BT_ / 256, 1), 512, 131072, stream>>>(
      hb, w16[5], up, nullptr, BT_, FF_, D_, D_, D_, FF_);

  // hu = silu(gate) * up  (in gate)
  silumul_kernel<<<(BT_ * FF_ / 8) / 256, 256, 0, stream>>>(gate, up);

  // Wd split-K=2: partials = hu @ Wd (per half-K), then out = p0 + p1 + x1
  if (!flat) conv(6);
  gemm256<2, 4, 256, 2><<<dim3(D_ / 256, BT_ / 256, 2), 512, 131072, stream>>>(
      gate, w16[6], parts, nullptr, BT_, D_, FF_, FF_, FF_, D_);
  addred_kernel<<<(BT_ * D_ / 4) / 256, 256, 0, stream>>>(parts, x1, out);
}